// Round 4
// baseline (276.347 us; speedup 1.0000x reference)
//
#include <hip/hip_runtime.h>

#define FEAT 32
#define SCAN_CHUNK 512

// ---- bf16 helpers via raw bits (header-independent) ------------------------
__device__ inline unsigned int pack2_bf16_rne(float x, float y) {
    unsigned int ux = __float_as_uint(x);
    unsigned int uy = __float_as_uint(y);
    unsigned int bx = (ux + 0x7fffu + ((ux >> 16) & 1u)) >> 16;
    unsigned int by = (uy + 0x7fffu + ((uy >> 16) & 1u)) >> 16;
    return (by << 16) | (bx & 0xffffu);
}
__device__ inline float bf16lo_to_f32(unsigned int u) { return __uint_as_float(u << 16); }
__device__ inline float bf16hi_to_f32(unsigned int u) { return __uint_as_float(u & 0xffff0000u); }

// ---------------------------------------------------------------------------
// feat f32 -> packed bf16x2 (halves gather bytes in the hot kernel)
// ---------------------------------------------------------------------------
__global__ __launch_bounds__(256) void cvt_kernel(
    const float* __restrict__ feat, unsigned int* __restrict__ fb, int nPairs)
{
    int i = blockIdx.x * blockDim.x + threadIdx.x;
    if (i >= nPairs) return;
    float2 v = ((const float2*)feat)[i];
    fb[i] = pack2_bf16_rne(v.x, v.y);
}

// ---------------------------------------------------------------------------
// CSR build: histogram -> 3-pass exclusive scan -> place
// ---------------------------------------------------------------------------
__global__ __launch_bounds__(256) void hist_kernel(
    const int* __restrict__ dst, int* __restrict__ cnt, int nEdges)
{
    int i = blockIdx.x * blockDim.x + threadIdx.x;
    if (i < nEdges) atomicAdd(&cnt[dst[i]], 1);
}

__global__ __launch_bounds__(256) void scanA_kernel(
    const int* __restrict__ cnt, int* __restrict__ partial, int nNodes)
{
    __shared__ int red[256];
    int t = threadIdx.x, base = blockIdx.x * SCAN_CHUNK;
    int i0 = base + t, i1 = base + t + 256;
    int x = ((i0 < nNodes) ? cnt[i0] : 0) + ((i1 < nNodes) ? cnt[i1] : 0);
    red[t] = x; __syncthreads();
    for (int s = 128; s > 0; s >>= 1) { if (t < s) red[t] += red[t + s]; __syncthreads(); }
    if (t == 0) partial[blockIdx.x] = red[0];
}

__global__ __launch_bounds__(256) void scanB_kernel(
    const int* __restrict__ partial, int* __restrict__ blockOff, int nB)
{
    __shared__ int buf[2][256];
    int t = threadIdx.x;
    int v = (t < nB) ? partial[t] : 0;
    buf[0][t] = v; int sp = 0; __syncthreads();
    for (int off = 1; off < 256; off <<= 1) {
        int w = buf[sp][t];
        if (t >= off) w += buf[sp][t - off];
        buf[1 - sp][t] = w; sp = 1 - sp;
        __syncthreads();
    }
    if (t < nB) blockOff[t] = buf[sp][t] - v;   // exclusive
}

__global__ __launch_bounds__(256) void scanC_kernel(
    const int* __restrict__ cnt, const int* __restrict__ blockOff,
    int* __restrict__ rowptr, int* __restrict__ cursor, int nNodes, int nEdges)
{
    __shared__ int buf[2][256];
    int t = threadIdx.x, b = blockIdx.x;
    int base = b * SCAN_CHUNK;
    int i0 = base + 2 * t, i1 = i0 + 1;
    int e0 = (i0 < nNodes) ? cnt[i0] : 0;
    int e1 = (i1 < nNodes) ? cnt[i1] : 0;
    int s = e0 + e1;
    buf[0][t] = s; int sp = 0; __syncthreads();
    for (int off = 1; off < 256; off <<= 1) {
        int w = buf[sp][t];
        if (t >= off) w += buf[sp][t - off];
        buf[1 - sp][t] = w; sp = 1 - sp;
        __syncthreads();
    }
    int excl = buf[sp][t] - s;
    int g = blockOff[b];
    if (i0 < nNodes) { int r = g + excl;      rowptr[i0] = r; cursor[i0] = r; }
    if (i1 < nNodes) { int r = g + excl + e0; rowptr[i1] = r; cursor[i1] = r; }
    if (b == 0 && t == 0) rowptr[nNodes] = nEdges;
}

__global__ __launch_bounds__(256) void place_kernel(
    const int* __restrict__ src, const int* __restrict__ dst,
    int* __restrict__ cursor, int* __restrict__ eidx, int nEdges)
{
    int i = blockIdx.x * blockDim.x + threadIdx.x;
    if (i >= nEdges) return;
    int d = dst[i];
    int pos = atomicAdd(&cursor[d], 1);
    eidx[pos] = src[i];
}

// ---------------------------------------------------------------------------
// Gather-accumulate: one wave per node, NO atomics.
// 16-lane groups each handle one edge's 64B bf16 row; 4 edges in flight/wave.
// Butterfly-reduce across groups, write f32 hN row (128B coalesced).
// ---------------------------------------------------------------------------
__global__ __launch_bounds__(256) void gather_kernel(
    const unsigned int* __restrict__ fb, const int* __restrict__ rowptr,
    const int* __restrict__ eidx, float* __restrict__ hN, int nNodes)
{
    int node = (blockIdx.x * 256 + threadIdx.x) >> 6;
    if (node >= nNodes) return;
    int lane = threadIdx.x & 63;
    int g = lane >> 4, fl = lane & 15;
    int beg = rowptr[node], end = rowptr[node + 1];

    float a0 = 0.f, a1 = 0.f;
    for (int e = beg + g; e < end; e += 4) {
        int s = eidx[e];                       // uniform within 16-lane group
        unsigned int u = fb[s * 16 + fl];      // 64B contiguous per group
        a0 += bf16lo_to_f32(u);
        a1 += bf16hi_to_f32(u);
    }
    a0 += __shfl_xor(a0, 16); a1 += __shfl_xor(a1, 16);
    a0 += __shfl_xor(a0, 32); a1 += __shfl_xor(a1, 32);

    if (lane < 16) {
        float2 w; w.x = a0; w.y = a1;
        ((float2*)hN)[(size_t)node * 16 + fl] = w;
    }
}

// ---------------------------------------------------------------------------
// Projection: out[n,o] = b[o] + sum_f hN[n,f] * W[o,f]   (f32 hN)
// ---------------------------------------------------------------------------
__global__ __launch_bounds__(256) void proj_kernel(
    const float* __restrict__ hN, const float* __restrict__ W,
    const float* __restrict__ b, float* __restrict__ out, int nNodes)
{
    __shared__ float Ws[32][33];
    __shared__ float bs[32];
    __shared__ float hs[8][32];

    int t = threadIdx.x;
    if (t < 32) bs[t] = b[t];
    for (int i = t; i < 32 * 32; i += 256) Ws[i >> 5][i & 31] = W[i];

    int rowBase = blockIdx.x * 8;
    int loadIdx = rowBase * FEAT + t;
    hs[t >> 5][t & 31] = (loadIdx < nNodes * FEAT) ? hN[loadIdx] : 0.0f;
    __syncthreads();

    int nl = t >> 5, o = t & 31;
    int n = rowBase + nl;
    if (n >= nNodes) return;

    float acc = bs[o];
    #pragma unroll
    for (int f = 0; f < FEAT; ++f) acc += hs[nl][f] * Ws[o][f];
    out[n * FEAT + o] = acc;
}

// ---------------------------------------------------------------------------
// Fallback (ws too small): f32 atomic scatter (round-1 proven path)
// ---------------------------------------------------------------------------
__global__ __launch_bounds__(256) void scatter_f32_kernel(
    const float* __restrict__ feat, const int* __restrict__ src,
    const int* __restrict__ dst, float* __restrict__ hN, int nEdges)
{
    int idx = blockIdx.x * blockDim.x + threadIdx.x;
    if (idx >= nEdges * FEAT) return;
    int e = idx >> 5, f = idx & 31;
    atomicAdd(&hN[dst[e] * FEAT + f], feat[src[e] * FEAT + f]);
}

extern "C" void kernel_launch(void* const* d_in, const int* in_sizes, int n_in,
                              void* d_out, int out_size, void* d_ws, size_t ws_size,
                              hipStream_t stream)
{
    const float* feat = (const float*)d_in[0];
    const int*   src  = (const int*)d_in[1];
    const int*   dst  = (const int*)d_in[2];
    const float* W    = (const float*)d_in[3];
    const float* b    = (const float*)d_in[4];
    float* out = (float*)d_out;

    int nNodes = in_sizes[0] / FEAT;
    int nEdges = in_sizes[1];
    int nScanBlocks = (nNodes + SCAN_CHUNK - 1) / SCAN_CHUNK;

    auto align256 = [](size_t x) { return (x + 255) & ~(size_t)255; };
    size_t sz_fb   = align256((size_t)nNodes * 16 * 4);
    size_t sz_hN   = align256((size_t)nNodes * 32 * 4);
    size_t sz_cnt  = align256((size_t)nNodes * 4);
    size_t sz_rp   = align256(((size_t)nNodes + 1) * 4);
    size_t sz_cur  = sz_cnt;
    size_t sz_eidx = align256((size_t)nEdges * 4);
    size_t sz_scan = align256(2 * 256 * 4);
    size_t total = sz_fb + sz_hN + sz_cnt + sz_rp + sz_cur + sz_eidx + sz_scan;

    if (ws_size >= total && nScanBlocks <= 256) {
        char* p = (char*)d_ws;
        unsigned int* fb = (unsigned int*)p;  p += sz_fb;
        float* hN        = (float*)p;         p += sz_hN;
        int* cnt         = (int*)p;           p += sz_cnt;
        int* rowptr      = (int*)p;           p += sz_rp;
        int* cursor      = (int*)p;           p += sz_cur;
        int* eidx        = (int*)p;           p += sz_eidx;
        int* partials    = (int*)p;           // [256] partial + [256] blockOff
        int* blockOff    = partials + 256;

        (void)hipMemsetAsync(cnt, 0, (size_t)nNodes * 4, stream);

        int nPairs = nNodes * 16;
        cvt_kernel<<<(nPairs + 255) / 256, 256, 0, stream>>>(feat, fb, nPairs);
        hist_kernel<<<(nEdges + 255) / 256, 256, 0, stream>>>(dst, cnt, nEdges);
        scanA_kernel<<<nScanBlocks, 256, 0, stream>>>(cnt, partials, nNodes);
        scanB_kernel<<<1, 256, 0, stream>>>(partials, blockOff, nScanBlocks);
        scanC_kernel<<<nScanBlocks, 256, 0, stream>>>(cnt, blockOff, rowptr, cursor, nNodes, nEdges);
        place_kernel<<<(nEdges + 255) / 256, 256, 0, stream>>>(src, dst, cursor, eidx, nEdges);
        gather_kernel<<<(nNodes + 3) / 4, 256, 0, stream>>>(fb, rowptr, eidx, hN, nNodes);
        proj_kernel<<<(nNodes + 7) / 8, 256, 0, stream>>>(hN, W, b, out, nNodes);
    } else {
        // fallback: proven f32 atomic path (needs only hN = N*32 f32)
        float* hN = (float*)d_ws;
        (void)hipMemsetAsync(hN, 0, (size_t)nNodes * 32 * 4, stream);
        long long totalScatter = (long long)nEdges * FEAT;
        scatter_f32_kernel<<<(int)((totalScatter + 255) / 256), 256, 0, stream>>>(
            feat, src, dst, hN, nEdges);
        proj_kernel<<<(nNodes + 7) / 8, 256, 0, stream>>>(hN, W, b, out, nNodes);
    }
}